// Round 1
// baseline (411.656 us; speedup 1.0000x reference)
//
#include <hip/hip_runtime.h>
#include <cstdint>

constexpr int NV = 32000;   // vocab / N
constexpr int NE = 256;     // embed dim
constexpr int NH = 512;     // hidden / K (per split half)
constexpr int NB = 8;       // batch
constexpr int NS = 16;      // seq len
constexpr int NT = 20;      // time steps
constexpr int NSTEP = NS * NT;      // 320
constexpr int NM = NSTEP * NB;      // 2560 GEMM rows
constexpr int KD = 1024;            // split K (hi | lo)
constexpr float TH1 = 0.8f;
constexpr float TH2 = 1.0f;

typedef _Float16 f16x8 __attribute__((ext_vector_type(8)));
typedef _Float16 f16x4 __attribute__((ext_vector_type(4)));
typedef float f32x4 __attribute__((ext_vector_type(4)));

__device__ inline float clip01(float v) { return fminf(fmaxf(v, 0.f), 1.f); }

#define GL_LDS(gp, lp) \
  __builtin_amdgcn_global_load_lds((const __attribute__((address_space(1))) void*)(gp), \
                                   (__attribute__((address_space(3))) void*)(lp), 16, 0, 0)

// ---------------- K1: cur1[b][s][h] = embed[x[b,s],:] . W1[h,:] + b1[h] ----------------
__global__ void k_cur1(const int* __restrict__ x, const float* __restrict__ embed,
                       const float* __restrict__ W1, const float* __restrict__ b1,
                       float* __restrict__ cur1) {
  __shared__ float e[NE];
  int bs = blockIdx.x;                 // b*NS + s
  int row = x[bs];
  e[threadIdx.x] = embed[(size_t)row * NE + threadIdx.x];
  __syncthreads();
  for (int hh = 0; hh < 2; ++hh) {
    int h = threadIdx.x + hh * 256;
    const float* w = W1 + (size_t)h * NE;
    float acc = 0.f;
#pragma unroll 8
    for (int k = 0; k < NE; ++k) acc = fmaf(e[k], w[k], acc);
    cur1[(size_t)bs * NH + h] = acc + b1[h];
  }
}

// ---------------- K2: leaky recurrence -> spike matrix A2 (fp16), final mem1 ----------------
__global__ void k_spk1(const float* __restrict__ cur1, const float* __restrict__ pbeta1,
                       _Float16* __restrict__ A2, float* __restrict__ mem1_out) {
  int g = blockIdx.x * blockDim.x + threadIdx.x;   // 4096 = NB*NH
  int b = g >> 9, h = g & 511;
  float bc = clip01(pbeta1[0]);
  float mem = 0.f;
  const _Float16 one  = (_Float16)1.0f;
  const _Float16 sc   = (_Float16)4.8828125e-4f;   // 2^-11, exact in fp16
  const _Float16 zero = (_Float16)0.0f;
  for (int s = 0; s < NS; ++s) {
    float c = cur1[((size_t)b * NS + s) * NH + h];
    for (int t = 0; t < NT; ++t) {
      float rst = (mem > TH1) ? TH1 : 0.f;                       // reset1*TH1 (exact)
      mem = __fsub_rn(__fadd_rn(__fmul_rn(bc, mem), c), rst);    // ((b*m)+c)-r, np order
      bool spk = mem > TH1;
      size_t m = (size_t)(s * NT + t) * NB + b;
      A2[m * KD + h]       = spk ? one : zero;   // hi half: spk1
      A2[m * KD + 512 + h] = spk ? sc  : zero;   // lo half: spk1 * 2^-11
    }
  }
  mem1_out[g] = mem;   // g == b*NH+h
}

// ---------------- K3: split W2 (V,H) fp32 -> B2 (V, [hi(512)|lo(512)]) fp16 ----------------
__global__ void k_split(const float* __restrict__ W2, _Float16* __restrict__ B2) {
  int g = blockIdx.x * blockDim.x + threadIdx.x;   // NV*NH/4 threads
  int v = g >> 7;
  int h4 = (g & 127) * 4;
  const float4 w4 = *(const float4*)&W2[(size_t)v * NH + h4];
  const float* wf = (const float*)&w4;
  f16x4 hv, lv;
#pragma unroll
  for (int i = 0; i < 4; ++i) {
    float w = wf[i];
    _Float16 h16 = (fabsf(w) < 6.103515625e-05f) ? (_Float16)0.f : (_Float16)w; // avoid fp16 denormal hi
    float r = w - (float)h16;           // exact (Sterbenz)
    hv[i] = h16;
    lv[i] = (_Float16)(r * 2048.0f);    // lo scaled by 2^11 (exact scaling)
  }
  *(f16x4*)&B2[(size_t)v * KD + h4]       = hv;
  *(f16x4*)&B2[(size_t)v * KD + 512 + h4] = lv;
}

// ---------------- GEMM: C[m,n] = A2[m,:] . B2[n,:]  (m97-style 128x128, f16 MFMA) ----------------
__global__ __launch_bounds__(256) void k_gemm(const _Float16* __restrict__ A,
                                              const _Float16* __restrict__ Bm,  // chunk base, row stride KD
                                              float* __restrict__ C, int cw) {
  int nwg = gridDim.x;
  int bid = blockIdx.x;
  // bijective XCD swizzle (m204 form)
  int q = nwg >> 3, r = nwg & 7;
  int xcd = bid & 7, lin = bid >> 3;
  int swz = ((xcd < r) ? xcd * (q + 1) : r * (q + 1) + (xcd - r) * q) + lin;
  int mt = swz % 20;          // m fastest -> consecutive blocks share the B n-panel
  int nt = swz / 20;

  const int tid = threadIdx.x;
  const int lane = tid & 63;
  const int wid = tid >> 6;            // 4 waves, 2x2
  const int wm = wid & 1, wn = wid >> 1;

  __shared__ __attribute__((aligned(16))) _Float16 As[128 * 64];
  __shared__ __attribute__((aligned(16))) _Float16 Bs[128 * 64];

  f32x4 acc[4][4] = {};
  const size_t m0 = (size_t)mt * 128;
  const size_t n0 = (size_t)nt * 128;

  // staging: per wave, per issue: 64 lanes x 16B = 8 rows of 128B
  const int lrow = lane >> 3;          // 0..7
  const int lcol = (lane & 7) * 8;     // element col within 64
  const _Float16* Abase = A  + (m0 + (size_t)wid * 8 + lrow) * KD + lcol;
  const _Float16* Bbase = Bm + (n0 + (size_t)wid * 8 + lrow) * KD + lcol;
  _Float16* AsW = As + wid * 8 * 64;   // wave-uniform LDS base
  _Float16* BsW = Bs + wid * 8 * 64;

  const int lr  = lane & 15;
  const int lk8 = (lane >> 4) * 8;

  for (int kk = 0; kk < KD; kk += 64) {
    __syncthreads();                   // previous compute done before overwrite
#pragma unroll
    for (int i = 0; i < 4; ++i) {
      GL_LDS(Abase + (size_t)i * 32 * KD + kk, AsW + i * 32 * 64);
      GL_LDS(Bbase + (size_t)i * 32 * KD + kk, BsW + i * 32 * 64);
    }
    __syncthreads();                   // drains vmcnt: tiles resident
#pragma unroll
    for (int kf = 0; kf < 2; ++kf) {
      f16x8 af[4], bf[4];
#pragma unroll
      for (int mi = 0; mi < 4; ++mi)
        af[mi] = *(const f16x8*)&As[(wm * 64 + mi * 16 + lr) * 64 + kf * 32 + lk8];
#pragma unroll
      for (int ni = 0; ni < 4; ++ni)
        bf[ni] = *(const f16x8*)&Bs[(wn * 64 + ni * 16 + lr) * 64 + kf * 32 + lk8];
#pragma unroll
      for (int ni = 0; ni < 4; ++ni)
#pragma unroll
        for (int mi = 0; mi < 4; ++mi)
          acc[mi][ni] = __builtin_amdgcn_mfma_f32_16x16x32_f16(af[mi], bf[ni], acc[mi][ni], 0, 0, 0);
    }
  }
  // epilogue: C/D layout col=lane&15, row=(lane>>4)*4+j  (m89-verified)
  const int cr = (lane >> 4) * 4;
  const int cc = lane & 15;
#pragma unroll
  for (int mi = 0; mi < 4; ++mi)
#pragma unroll
    for (int ni = 0; ni < 4; ++ni) {
      size_t mrow = m0 + wm * 64 + mi * 16 + cr;
      size_t ncol = n0 + wn * 64 + ni * 16 + cc;
#pragma unroll
      for (int j = 0; j < 4; ++j)
        C[(mrow + j) * (size_t)cw + ncol] = acc[mi][ni][j];
    }
}

// ---------------- K4: synaptic recurrence per (b, v); emits outs, syn2, mem2 ----------------
__global__ void k_rec(const float* __restrict__ C, const float* __restrict__ b2,
                      const float* __restrict__ palpha2, const float* __restrict__ pbeta2,
                      float* __restrict__ out, int c0, int cw) {
  int g = blockIdx.x * blockDim.x + threadIdx.x;   // NB*cw
  int b = g / cw;
  int vl = g % cw;
  float a2 = clip01(palpha2[0]);
  float bc = clip01(pbeta2[0]);
  float b2v = b2[vl];                  // b2 passed pre-offset by c0
  float syn = 0.f, mem = 0.f;
  const float* Cp = C + vl;
  size_t vglob = (size_t)c0 + vl;
  for (int s = 0; s < NS; ++s) {
    for (int t = 0; t < NT; ++t) {
      size_t m = (size_t)((s * NT + t) * NB + b);
      float cur2 = __fadd_rn(Cp[m * (size_t)cw], b2v);
      float rst = (mem > TH2) ? 1.f : 0.f;                        // reset2 from OLD mem2
      syn = __fadd_rn(__fmul_rn(a2, syn), cur2);
      mem = __fsub_rn(__fadd_rn(__fmul_rn(bc, mem), syn), rst);
    }
    out[((size_t)b * NS + s) * NV + vglob] = (mem > TH2) ? 1.f : 0.f;  // spk2 at t=19
  }
  out[(size_t)4100096 + (size_t)b * NV + vglob] = syn;   // syn2
  out[(size_t)4356096 + (size_t)b * NV + vglob] = mem;   // mem2
}

extern "C" void kernel_launch(void* const* d_in, const int* in_sizes, int n_in,
                              void* d_out, int out_size, void* d_ws, size_t ws_size,
                              hipStream_t stream) {
  const int*   x     = (const int*)d_in[0];
  const float* embed = (const float*)d_in[1];
  const float* W1    = (const float*)d_in[2];
  const float* b1    = (const float*)d_in[3];
  const float* W2    = (const float*)d_in[4];
  const float* b2    = (const float*)d_in[5];
  const float* pb1   = (const float*)d_in[6];
  const float* pa2   = (const float*)d_in[7];
  const float* pb2   = (const float*)d_in[8];
  float* out = (float*)d_out;

  char* ws = (char*)d_ws;
  float* cur1 = (float*)ws;                                  // 8*16*512*4 = 262144 B
  _Float16* A2 = (_Float16*)(ws + 262144);                   // 2560*1024*2 = 5242880 B
  _Float16* B2 = (_Float16*)(ws + 262144 + (size_t)NM * KD * 2);
  size_t fixed = 262144 + (size_t)NM * KD * 2 + (size_t)NV * KD * 2;  // ~71.0 MB
  size_t coff = (fixed + 255) & ~(size_t)255;
  float* Cbuf = (float*)(ws + coff);

  size_t avail = (ws_size > coff) ? (ws_size - coff) : 0;
  long maxc = (long)(avail / ((size_t)NM * 4));              // columns that fit
  int CW = (int)((maxc / 128) * 128);
  if (CW > NV) CW = NV;
  if (CW < 128) CW = 128;   // minimal chunk; ws is expected to cover this

  hipLaunchKernelGGL(k_cur1, dim3(NB * NS), dim3(256), 0, stream, x, embed, W1, b1, cur1);
  hipLaunchKernelGGL(k_spk1, dim3(16), dim3(256), 0, stream, cur1, pb1, A2, out + 4096000);
  hipLaunchKernelGGL(k_split, dim3(NV * NH / 4 / 256), dim3(256), 0, stream, W2, B2);

  for (int c0 = 0; c0 < NV; c0 += CW) {
    int cw = NV - c0; if (cw > CW) cw = CW;
    int nwg = 20 * (cw / 128);
    hipLaunchKernelGGL(k_gemm, dim3(nwg), dim3(256), 0, stream,
                       A2, B2 + (size_t)c0 * KD, Cbuf, cw);
    hipLaunchKernelGGL(k_rec, dim3(NB * cw / 256), dim3(256), 0, stream,
                       Cbuf, b2 + c0, pa2, pb2, out, c0, cw);
  }
}

// Round 3
// 325.090 us; speedup vs baseline: 1.2663x; 1.2663x over previous
//
#include <hip/hip_runtime.h>
#include <cstdint>

constexpr int NV = 32000;   // vocab / N
constexpr int NE = 256;     // embed dim
constexpr int NH = 512;     // hidden / K (per split half)
constexpr int NB = 8;       // batch
constexpr int NS = 16;      // seq len
constexpr int NT = 20;      // time steps
constexpr int NSTEP = NS * NT;      // 320
constexpr int NM = NSTEP * NB;      // 2560 GEMM rows
constexpr int KD = 1024;            // split K (hi | lo)
constexpr float TH1 = 0.8f;
constexpr float TH2 = 1.0f;

typedef _Float16 f16x8 __attribute__((ext_vector_type(8)));
typedef _Float16 f16x4 __attribute__((ext_vector_type(4)));
typedef float f32x4 __attribute__((ext_vector_type(4)));

__device__ inline float clip01(float v) { return fminf(fmaxf(v, 0.f), 1.f); }

#define GL_LDS(gp, lp) \
  __builtin_amdgcn_global_load_lds((const __attribute__((address_space(1))) void*)(gp), \
                                   (__attribute__((address_space(3))) void*)(lp), 16, 0, 0)

__device__ inline void barsched() {
  __builtin_amdgcn_s_barrier();
  __builtin_amdgcn_sched_barrier(0);
}

// ---------------- K1: cur1[b][s][h] = embed[x[b,s],:] . W1[h,:] + b1[h] ----------------
__global__ void k_cur1(const int* __restrict__ x, const float* __restrict__ embed,
                       const float* __restrict__ W1, const float* __restrict__ b1,
                       float* __restrict__ cur1) {
  __shared__ float e[NE];
  int bs = blockIdx.x;                 // b*NS + s
  int row = x[bs];
  e[threadIdx.x] = embed[(size_t)row * NE + threadIdx.x];
  __syncthreads();
  for (int hh = 0; hh < 2; ++hh) {
    int h = threadIdx.x + hh * 256;
    const float* w = W1 + (size_t)h * NE;
    float acc = 0.f;
#pragma unroll 8
    for (int k = 0; k < NE; ++k) acc = fmaf(e[k], w[k], acc);
    cur1[(size_t)bs * NH + h] = acc + b1[h];
  }
}

// ---------------- K2: leaky recurrence -> spike matrix A2 (fp16), final mem1 ----------------
__global__ void k_spk1(const float* __restrict__ cur1, const float* __restrict__ pbeta1,
                       _Float16* __restrict__ A2, float* __restrict__ mem1_out) {
  int g = blockIdx.x * blockDim.x + threadIdx.x;   // 4096 = NB*NH
  int b = g >> 9, h = g & 511;
  float bc = clip01(pbeta1[0]);
  float mem = 0.f;
  const _Float16 one  = (_Float16)1.0f;
  const _Float16 sc   = (_Float16)4.8828125e-4f;   // 2^-11, exact in fp16
  const _Float16 zero = (_Float16)0.0f;
  for (int s = 0; s < NS; ++s) {
    float c = cur1[((size_t)b * NS + s) * NH + h];
    for (int t = 0; t < NT; ++t) {
      float rst = (mem > TH1) ? TH1 : 0.f;                       // reset1*TH1 (exact)
      mem = __fsub_rn(__fadd_rn(__fmul_rn(bc, mem), c), rst);    // ((b*m)+c)-r, np order
      bool spk = mem > TH1;
      size_t m = (size_t)(s * NT + t) * NB + b;
      A2[m * KD + h]       = spk ? one : zero;   // hi half: spk1
      A2[m * KD + 512 + h] = spk ? sc  : zero;   // lo half: spk1 * 2^-11
    }
  }
  mem1_out[g] = mem;   // g == b*NH+h
}

// ---------------- Fused: W2-split + GEMM(128x128 tiles over m) + synaptic recurrence ----------------
// One block per 128-wide n-strip. 512 threads = 8 waves (2m x 4n), wave tile 64x32.
// Per m-tile (16 time steps): K=1024 GEMM into regs -> C tile in LDS -> recurrence update.
__global__ __launch_bounds__(512) void k_fused(
    const _Float16* __restrict__ A,   // A2 [2560][1024] (spikes hi|lo)
    const float* __restrict__ W2,     // [32000][512] fp32
    _Float16* __restrict__ B2,        // [32000][1024] f16 hi|lo scratch
    const float* __restrict__ b2,
    const float* __restrict__ pa2, const float* __restrict__ pb2,
    float* __restrict__ out) {
  __shared__ __attribute__((aligned(16))) _Float16 As[2 * 128 * 64];   // 32 KB dbuf
  __shared__ __attribute__((aligned(16))) _Float16 Bs[2 * 128 * 64];   // 32 KB dbuf
  __shared__ __attribute__((aligned(16))) float    Cl[128 * 132];      // 66 KB (pad +4)

  const int tid  = threadIdx.x;
  const int lane = tid & 63;
  const int wid  = tid >> 6;           // 0..7
  const int wm   = wid >> 2;           // 0..1 (m half)
  const int wn   = wid & 3;            // 0..3 (n quarter)
  const int n0   = blockIdx.x * 128;

  // ---- phase 0: convert this block's W2 strip -> B2 (hi | lo*2^11) f16 ----
  for (int it = 0; it < 32; ++it) {
    int idx = it * 512 + tid;          // 0..16383
    int v  = idx >> 7;                 // 0..127
    int c4 = (idx & 127) * 4;          // 0..508
    const float4 w4 = *(const float4*)&W2[(size_t)(n0 + v) * NH + c4];
    const float* wf = (const float*)&w4;
    f16x4 hv, lv;
#pragma unroll
    for (int i = 0; i < 4; ++i) {
      float w = wf[i];
      _Float16 h16 = (fabsf(w) < 6.103515625e-05f) ? (_Float16)0.f : (_Float16)w;
      hv[i] = h16;
      lv[i] = (_Float16)((w - (float)h16) * 2048.0f);   // exact residual * 2^11
    }
    *(f16x4*)&B2[(size_t)(n0 + v) * KD + c4]       = hv;
    *(f16x4*)&B2[(size_t)(n0 + v) * KD + 512 + c4] = lv;
  }
  asm volatile("s_waitcnt vmcnt(0)" ::: "memory");   // stores drained -> L2 visible
  barsched();

  // ---- recurrence state (registers) ----
  const float a2 = clip01(pa2[0]);
  const float bc = clip01(pb2[0]);
  const int vv = tid & 127;            // owned column
  const int bbase = tid >> 7;          // 0..3 ; owns b = bbase, bbase+4
  const float b2v = b2[n0 + vv];
  float syn[2] = {0.f, 0.f};
  float mem[2] = {0.f, 0.f};

  f32x4 acc[4][2] = {};

  // ---- staging geometry (XOR-swizzled global source, linear LDS dest) ----
  // Per stage call: 4 GL_LDS per wave -> 2x 64 rows of A + 2x 64 rows of B (full 128-row tiles).
  const int srow = tid >> 3;                              // 0..63 (lower half row)
  const int scol = ((tid & 7) * 8) ^ ((srow & 7) * 8);    // swizzled element col (0..56)
  const _Float16* gA = A + (size_t)srow * KD + scol;
  const _Float16* gB = B2 + (size_t)(n0 + srow) * KD + scol;
  _Float16* ldsA0 = As + wid * 512;                       // wave-uniform base (lower half)
  _Float16* ldsB0 = Bs + wid * 512;

  auto stage = [&](int buf, int mt, int kk) {
    const size_t mo = (size_t)mt * 128 * KD;
    GL_LDS(gA + mo + kk,                    ldsA0 + buf * 8192);          // A rows 0..63
    GL_LDS(gA + mo + (size_t)64 * KD + kk,  ldsA0 + buf * 8192 + 4096);   // A rows 64..127
    GL_LDS(gB + kk,                         ldsB0 + buf * 8192);          // B rows 0..63
    GL_LDS(gB + (size_t)64 * KD + kk,       ldsB0 + buf * 8192 + 4096);   // B rows 64..127
  };

  const int lr  = lane & 15;
  const int lk8 = (lane >> 4) * 8;
  const int sw  = (lr & 7) * 8;                           // read-side swizzle
  const int cr  = (lane >> 4) * 4, cc = lane & 15;

  stage(0, 0, 0);
  for (int mt = 0; mt < 20; ++mt) {
    for (int t = 0; t < 16; ++t) {
      const int buf = t & 1;
      if (mt == 19 && t == 15) {
        asm volatile("s_waitcnt vmcnt(0)" ::: "memory");
      } else {
        stage(buf ^ 1, (t == 15) ? mt + 1 : mt, (t == 15) ? 0 : (t + 1) * 64);
        asm volatile("s_waitcnt vmcnt(4)" ::: "memory");  // current buf's 4 loads done
      }
      barsched();                                         // all waves: buf resident
#pragma unroll
      for (int kf = 0; kf < 2; ++kf) {
        f16x8 af[4], bf[2];
        const int col = (kf * 32 + lk8) ^ sw;
#pragma unroll
        for (int mi = 0; mi < 4; ++mi)
          af[mi] = *(const f16x8*)&As[buf * 8192 + (wm * 64 + mi * 16 + lr) * 64 + col];
#pragma unroll
        for (int ni = 0; ni < 2; ++ni)
          bf[ni] = *(const f16x8*)&Bs[buf * 8192 + (wn * 32 + ni * 16 + lr) * 64 + col];
#pragma unroll
        for (int ni = 0; ni < 2; ++ni)
#pragma unroll
          for (int mi = 0; mi < 4; ++mi)
            acc[mi][ni] = __builtin_amdgcn_mfma_f32_16x16x32_f16(af[mi], bf[ni], acc[mi][ni], 0, 0, 0);
      }
      barsched();                                         // reads of buf done before overwrite
    }
    // ---- epilogue: acc -> Cl, then 16 recurrence steps ----
#pragma unroll
    for (int mi = 0; mi < 4; ++mi)
#pragma unroll
      for (int ni = 0; ni < 2; ++ni) {
#pragma unroll
        for (int j = 0; j < 4; ++j)
          Cl[(wm * 64 + mi * 16 + cr + j) * 132 + wn * 32 + ni * 16 + cc] = acc[mi][ni][j];
        acc[mi][ni] = (f32x4){0.f, 0.f, 0.f, 0.f};
      }
    barsched();                                           // Cl visible to all
    for (int st = 0; st < 16; ++st) {
      const int gs = mt * 16 + st;
#pragma unroll
      for (int p = 0; p < 2; ++p) {
        const int b = bbase + p * 4;
        float cur2 = __fadd_rn(Cl[(st * 8 + b) * 132 + vv], b2v);
        float rst = (mem[p] > TH2) ? 1.f : 0.f;            // reset from OLD mem2
        syn[p] = __fadd_rn(__fmul_rn(a2, syn[p]), cur2);
        mem[p] = __fsub_rn(__fadd_rn(__fmul_rn(bc, mem[p]), syn[p]), rst);
      }
      if (gs % 20 == 19) {                                 // last inner step of seq pos
        const int s = gs / 20;
#pragma unroll
        for (int p = 0; p < 2; ++p)
          out[((size_t)(bbase + p * 4) * NS + s) * NV + n0 + vv] = (mem[p] > TH2) ? 1.f : 0.f;
      }
    }
    barsched();                                           // Cl reads done before next write
  }
  // ---- final states ----
#pragma unroll
  for (int p = 0; p < 2; ++p) {
    out[(size_t)4100096 + (size_t)(bbase + p * 4) * NV + n0 + vv] = syn[p];  // syn2
    out[(size_t)4356096 + (size_t)(bbase + p * 4) * NV + n0 + vv] = mem[p];  // mem2
  }
}

extern "C" void kernel_launch(void* const* d_in, const int* in_sizes, int n_in,
                              void* d_out, int out_size, void* d_ws, size_t ws_size,
                              hipStream_t stream) {
  const int*   x     = (const int*)d_in[0];
  const float* embed = (const float*)d_in[1];
  const float* W1    = (const float*)d_in[2];
  const float* b1    = (const float*)d_in[3];
  const float* W2    = (const float*)d_in[4];
  const float* b2    = (const float*)d_in[5];
  const float* pb1   = (const float*)d_in[6];
  const float* pa2   = (const float*)d_in[7];
  const float* pb2   = (const float*)d_in[8];
  float* out = (float*)d_out;

  char* ws = (char*)d_ws;
  float* cur1 = (float*)ws;                                  // 262144 B
  _Float16* A2 = (_Float16*)(ws + 262144);                   // 2560*1024*2 = 5242880 B
  _Float16* B2 = (_Float16*)(ws + 262144 + (size_t)NM * KD * 2);  // 65.5 MB

  hipLaunchKernelGGL(k_cur1, dim3(NB * NS), dim3(256), 0, stream, x, embed, W1, b1, cur1);
  hipLaunchKernelGGL(k_spk1, dim3(16), dim3(256), 0, stream, cur1, pb1, A2, out + 4096000);
  hipLaunchKernelGGL(k_fused, dim3(NV / 128), dim3(512), 0, stream,
                     A2, W2, B2, b2, pa2, pb2, out);
}